// Round 20
// baseline (243.261 us; speedup 1.0000x reference)
//
#include <hip/hip_runtime.h>
#include <hip/hip_bf16.h>
#include <stdint.h>

#define B_ 8
#define T_ 2048
#define E_ 1024
#define H_ 1024
#define M_ (B_*T_)   // 16384

typedef __attribute__((ext_vector_type(8))) short bf16x8;
typedef __attribute__((ext_vector_type(4))) float f32x4;

__device__ __forceinline__ unsigned short f2bf(float f) {
  union { float f; unsigned int u; } v; v.f = f;
  unsigned int u = v.u;
  unsigned int r = u + 0x7fffu + ((u >> 16) & 1u);   // RNE (inputs finite)
  return (unsigned short)(r >> 16);
}

__device__ __forceinline__ float bf2f(unsigned short s) {
  union { unsigned int u; float f; } v; v.u = ((unsigned int)s) << 16;
  return v.f;
}

// async global->LDS, 16B per lane; LDS dest = wave-uniform base + lane*16
__device__ __forceinline__ void gload_lds16(const void* g, void* l) {
  __builtin_amdgcn_global_load_lds((const __attribute__((address_space(1))) void*)g,
                                   (__attribute__((address_space(3))) void*)l, 16, 0, 0);
}

#define MEMFENCE asm volatile("" ::: "memory")
#define BARRIER() do { MEMFENCE; __builtin_amdgcn_s_barrier(); MEMFENCE; } while (0)

// ---------- fused conversions: x->bf16 (blocks 0..8191) + W transpose (8192..11263) ----------
__global__ void conv_fused_kernel(const float* __restrict__ x, unsigned short* __restrict__ xb,
                                  const float* __restrict__ W0, const float* __restrict__ W1,
                                  const float* __restrict__ W2,
                                  unsigned short* __restrict__ T0, unsigned short* __restrict__ T1,
                                  unsigned short* __restrict__ T2) {
  __shared__ float tile[32][33];
  const int bid = blockIdx.x;
  if (bid < 8192) {
    // conv_x: 8 elems / thread
    int i = bid * 256 + threadIdx.x;
    const float4* src = (const float4*)(x + (size_t)i * 8);
    float4 a = src[0], b = src[1];
    uint4 o;
    o.x = (unsigned)f2bf(a.x) | ((unsigned)f2bf(a.y) << 16);
    o.y = (unsigned)f2bf(a.z) | ((unsigned)f2bf(a.w) << 16);
    o.z = (unsigned)f2bf(b.x) | ((unsigned)f2bf(b.y) << 16);
    o.w = (unsigned)f2bf(b.z) | ((unsigned)f2bf(b.w) << 16);
    *(uint4*)(xb + (size_t)i * 8) = o;
    return;
  }
  // conv_wT: W (E x H) -> wT (H x E) bf16, 32x32 tiles, float4 loads + ushort4 stores
  int id = bid - 8192;                 // 0..3071
  int z = id >> 10;                    // 0..2
  int rem = id & 1023;
  int k0 = (rem & 31) * 32;
  int n0 = (rem >> 5) * 32;
  const float* W = (z == 0) ? W0 : (z == 1) ? W1 : W2;
  unsigned short* Tt = (z == 0) ? T0 : (z == 1) ? T1 : T2;
  int t = threadIdx.x;
  int r = t >> 3, c4 = (t & 7) * 4;
  float4 v = *(const float4*)(W + (size_t)(k0 + r) * H_ + n0 + c4);
  tile[r][c4 + 0] = v.x; tile[r][c4 + 1] = v.y;
  tile[r][c4 + 2] = v.z; tile[r][c4 + 3] = v.w;
  __syncthreads();
  ushort4 o;
  o.x = f2bf(tile[c4 + 0][r]);
  o.y = f2bf(tile[c4 + 1][r]);
  o.z = f2bf(tile[c4 + 2][r]);
  o.w = f2bf(tile[c4 + 3][r]);
  *(ushort4*)(Tt + (size_t)(n0 + r) * E_ + k0 + c4) = o;
}

// ========== pipelined 128x128 core (4 waves, dbuf 64KB, counted vmcnt, 2 blocks/CU) ==========
// LDS buffer layout (bytes): A0 @0, B0 @16384, A1 @32768, B1 @49152.
__device__ __forceinline__ void stage128(const unsigned short* __restrict__ p, size_t stride,
                                         int kb0, short* buf, int lane, int wid) {
  const int srow = wid * 8 + (lane >> 3);
  const int scol = ((lane & 7) ^ (srow & 7)) * 8;
  short* l = buf + wid * 512;
#pragma unroll
  for (int i = 0; i < 4; ++i)
    gload_lds16(p + (size_t)(i * 32 + srow) * stride + kb0 + scol, l + i * 2048);
}

__device__ __forceinline__ void gemm_core_pipe(const unsigned short* __restrict__ Ap, size_t sA,
                                               const unsigned short* __restrict__ Bp, size_t sB,
                                               int NT, short* L, int lane, int wid, f32x4 acc[4][4]) {
  const int lo = lane & 15, hi = lane >> 4;
  const int wm = (wid >> 1) * 64, wn = (wid & 1) * 64;
  const int X0 = (hi << 4) ^ ((lo & 7) << 4);
  const int X1 = ((4 + hi) << 4) ^ ((lo & 7) << 4);
  const int laneA = (wm + lo) << 7;
  const int laneB = (wn + lo) << 7;

  bf16x8 a[4][2], b0[2][2], b1[2][2];

#define STA_(V) do { if ((V) < NT) stage128(Ap, sA, (V) * 64, L + (((V) & 1) ? 16384 : 0), lane, wid); } while (0)
#define STB_(V) do { if ((V) < NT) stage128(Bp, sB, (V) * 64, L + (((V) & 1) ? 24576 : 8192), lane, wid); } while (0)

  STA_(0); STB_(0); STA_(1); STB_(1);
  asm volatile("s_waitcnt vmcnt(8)" ::: "memory");
  BARRIER();
  __builtin_amdgcn_sched_barrier(0);
  {
    const char* Ac = (const char*)L;
    const char* Bc = (const char*)L + 16384;
#pragma unroll
    for (int mt = 0; mt < 4; ++mt) {
      a[mt][0] = *(const bf16x8*)(Ac + laneA + X0 + mt * 2048);
      a[mt][1] = *(const bf16x8*)(Ac + laneA + X1 + mt * 2048);
    }
#pragma unroll
    for (int nt = 0; nt < 2; ++nt) {
      b0[nt][0] = *(const bf16x8*)(Bc + laneB + X0 + nt * 2048);
      b0[nt][1] = *(const bf16x8*)(Bc + laneB + X1 + nt * 2048);
    }
    asm volatile("s_waitcnt lgkmcnt(0)" ::: "memory");
    __builtin_amdgcn_sched_barrier(0);
  }

  for (int U = 0; U < NT; ++U) {
    const char* Bc = (const char*)L + 16384 + (U & 1) * 32768;
    const char* An = (const char*)L + (((U + 1) & 1) ? 32768 : 0);
    const char* Bn = (const char*)L + 16384 + (((U + 1) & 1) ? 32768 : 0);
    const bool pf = (U + 1 < NT);

    // phase 1: MFMA a*b0 || read b1 || stage A(U+2)
    STA_(U + 2);
    __builtin_amdgcn_s_setprio(1);
#pragma unroll
    for (int mt = 0; mt < 2; ++mt)
#pragma unroll
      for (int nt = 0; nt < 2; ++nt)
#pragma unroll
        for (int kt = 0; kt < 2; ++kt)
          acc[mt][nt] = __builtin_amdgcn_mfma_f32_16x16x32_bf16(a[mt][kt], b0[nt][kt], acc[mt][nt], 0, 0, 0);
#pragma unroll
    for (int nt = 0; nt < 2; ++nt) {
      b1[nt][0] = *(const bf16x8*)(Bc + laneB + X0 + 4096 + nt * 2048);
      b1[nt][1] = *(const bf16x8*)(Bc + laneB + X1 + 4096 + nt * 2048);
    }
#pragma unroll
    for (int mt = 2; mt < 4; ++mt)
#pragma unroll
      for (int nt = 0; nt < 2; ++nt)
#pragma unroll
        for (int kt = 0; kt < 2; ++kt)
          acc[mt][nt] = __builtin_amdgcn_mfma_f32_16x16x32_bf16(a[mt][kt], b0[nt][kt], acc[mt][nt], 0, 0, 0);
    __builtin_amdgcn_s_setprio(0);
    asm volatile("s_waitcnt lgkmcnt(0)" ::: "memory");
    if (U + 2 < NT) asm volatile("s_waitcnt vmcnt(4)" ::: "memory");
    else            asm volatile("s_waitcnt vmcnt(0)" ::: "memory");
    BARRIER();
    __builtin_amdgcn_sched_barrier(0);

    // phase 2: MFMA a*b1 || read next a,b0 || stage B(U+2)
    STB_(U + 2);
    __builtin_amdgcn_s_setprio(1);
#pragma unroll
    for (int mt = 0; mt < 2; ++mt)
#pragma unroll
      for (int nt = 0; nt < 2; ++nt)
#pragma unroll
        for (int kt = 0; kt < 2; ++kt)
          acc[mt][2 + nt] = __builtin_amdgcn_mfma_f32_16x16x32_bf16(a[mt][kt], b1[nt][kt], acc[mt][2 + nt], 0, 0, 0);
    if (pf) {
#pragma unroll
      for (int mt = 0; mt < 2; ++mt) {
        a[mt][0] = *(const bf16x8*)(An + laneA + X0 + mt * 2048);
        a[mt][1] = *(const bf16x8*)(An + laneA + X1 + mt * 2048);
      }
#pragma unroll
      for (int nt = 0; nt < 2; ++nt) {
        b0[nt][0] = *(const bf16x8*)(Bn + laneB + X0 + nt * 2048);
        b0[nt][1] = *(const bf16x8*)(Bn + laneB + X1 + nt * 2048);
      }
    }
#pragma unroll
    for (int mt = 2; mt < 4; ++mt)
#pragma unroll
      for (int nt = 0; nt < 2; ++nt)
#pragma unroll
        for (int kt = 0; kt < 2; ++kt)
          acc[mt][2 + nt] = __builtin_amdgcn_mfma_f32_16x16x32_bf16(a[mt][kt], b1[nt][kt], acc[mt][2 + nt], 0, 0, 0);
    if (pf) {
#pragma unroll
      for (int mt = 2; mt < 4; ++mt) {
        a[mt][0] = *(const bf16x8*)(An + laneA + X0 + mt * 2048);
        a[mt][1] = *(const bf16x8*)(An + laneA + X1 + mt * 2048);
      }
    }
    __builtin_amdgcn_s_setprio(0);
    asm volatile("s_waitcnt lgkmcnt(0)" ::: "memory");
    BARRIER();
    __builtin_amdgcn_sched_barrier(0);
  }
#undef STA_
#undef STB_
}

// ---------- fused QKV GEMM on the pipelined 128x128 core ----------
// grid: (24 = which*8 + n-tile, 128 M-tiles). x fastest -> A-panel L2 sharing.
// which==2 (vT) epilogue: LDS-bounce [d][m] tile -> coalesced 256B-row b128 stores.
__global__ __launch_bounds__(256, 2)
void gemm_qkv_kernel(const unsigned short* __restrict__ xb,
                     const unsigned short* __restrict__ wqT, const unsigned short* __restrict__ wkT,
                     const unsigned short* __restrict__ wvT,
                     const float* __restrict__ bq, const float* __restrict__ bk,
                     const float* __restrict__ bv,
                     unsigned short* __restrict__ qb, unsigned short* __restrict__ kb,
                     unsigned short* __restrict__ vb) {
  __shared__ short L[32768];   // 64KB double-buffered; reused by vT epilogue bounce
  const int which = blockIdx.x >> 3;
  const int ncol0 = (blockIdx.x & 7) * 128;
  const unsigned short* Bt = (which == 0) ? wqT : (which == 1) ? wkT : wvT;
  const float* bias = (which == 0) ? bq : (which == 1) ? bk : bv;
  unsigned short* outp = (which == 0) ? qb : (which == 1) ? kb : vb;
  const int m0 = blockIdx.y * 128;
  int tid = threadIdx.x, lane = tid & 63, wid = tid >> 6;
  int wm = (wid >> 1) * 64, wn = (wid & 1) * 64;

  f32x4 acc[4][4];
#pragma unroll
  for (int i = 0; i < 4; ++i)
#pragma unroll
    for (int j = 0; j < 4; ++j)
#pragma unroll
      for (int r = 0; r < 4; ++r) acc[i][j][r] = 0.f;

  gemm_core_pipe(xb + (size_t)m0 * E_, E_,
                 Bt + (size_t)ncol0 * E_, E_, E_ / 64,
                 L, lane, wid, acc);

  if (which == 2) {
    // bounce vT tile through LDS: Ep[tc][tr], 256B rows, granule-XOR swizzle (tc&15)<<4
    char* Ep = (char*)L;   // 32KB used; safe: core exited fully drained + barrier
#pragma unroll
    for (int nt = 0; nt < 4; ++nt) {
      int tc = wn + nt * 16 + (lane & 15);
      float bb = bias[ncol0 + tc];
      char* rowp = Ep + tc * 256;
      int xr = (tc & 15) << 4;
#pragma unroll
      for (int mt = 0; mt < 4; ++mt) {
        int tr = wm + mt * 16 + (lane >> 4) * 4;
        ushort4 o2;
        o2.x = f2bf(acc[mt][nt][0] + bb);
        o2.y = f2bf(acc[mt][nt][1] + bb);
        o2.z = f2bf(acc[mt][nt][2] + bb);
        o2.w = f2bf(acc[mt][nt][3] + bb);
        *(ushort4*)(rowp + ((tr * 2) ^ xr)) = o2;
      }
    }
    __syncthreads();
    {
      const int d = tid >> 1, hf = tid & 1;
      const char* rowp = Ep + d * 256;
      const int xr = (d & 15) << 4;
      unsigned short* gp = outp + (size_t)(ncol0 + d) * M_ + m0;
#pragma unroll
      for (int k = 0; k < 8; ++k) {
        int g = hf * 8 + k;
        bf16x8 v = *(const bf16x8*)(rowp + ((g << 4) ^ xr));
        *(bf16x8*)(gp + g * 8) = v;
      }
    }
  } else {
#pragma unroll
    for (int nt = 0; nt < 4; ++nt) {
      int gcol = ncol0 + wn + nt * 16 + (lane & 15);
      float bb = bias[gcol];
#pragma unroll
      for (int mt = 0; mt < 4; ++mt) {
        int grow = m0 + wm + mt * 16 + (lane >> 4) * 4;
#pragma unroll
        for (int r = 0; r < 4; ++r)
          outp[(size_t)(grow + r) * H_ + gcol] = f2bf(acc[mt][nt][r] + bb);
      }
    }
  }
}

// ---------- S = (Q K^T) * scale, causal lower-tri 128x128 tiles, bf16 out ----------
// 1024 blocks (exactly 2 dispatch waves @2/CU); blocks 0..63 do a second tile.
__global__ __launch_bounds__(256, 2)
void sgemm_kernel(const unsigned short* __restrict__ qb, const unsigned short* __restrict__ kb,
                  unsigned short* __restrict__ S) {
  __shared__ short L[32768];   // 64KB double-buffered
  int tid = threadIdx.x, lane = tid & 63, wid = tid >> 6;
  int wm = (wid >> 1) * 64, wn = (wid & 1) * 64;
  const int npass = (blockIdx.x < 64) ? 2 : 1;

  for (int pass = 0; pass < npass; ++pass) {
    int id = blockIdx.x + pass * 1024;
    int b = id & 7, t = id >> 3;            // batch-fastest: same batch -> same XCD
    int mb = 0;
    while ((mb + 1) * (mb + 2) / 2 <= t) ++mb;
    int nb = t - mb * (mb + 1) / 2;         // nb <= mb (lower triangle)
    const size_t bT = (size_t)b * T_;

    f32x4 acc[4][4];
#pragma unroll
    for (int i = 0; i < 4; ++i)
#pragma unroll
      for (int j = 0; j < 4; ++j)
#pragma unroll
        for (int r = 0; r < 4; ++r) acc[i][j][r] = 0.f;

    gemm_core_pipe(qb + (bT + mb * 128) * (size_t)H_, H_,
                   kb + (bT + nb * 128) * (size_t)H_, H_, H_ / 64,
                   L, lane, wid, acc);

#pragma unroll
    for (int nt = 0; nt < 4; ++nt) {
      int gcol = nb * 128 + wn + nt * 16 + (lane & 15);
#pragma unroll
      for (int mt = 0; mt < 4; ++mt) {
        int grow = mb * 128 + wm + mt * 16 + (lane >> 4) * 4;
#pragma unroll
        for (int r = 0; r < 4; ++r)
          S[(bT + grow + r) * (size_t)T_ + gcol] = f2bf(acc[mt][nt][r] * 0.03125f);
      }
    }
    if (pass + 1 < npass) { BARRIER(); }   // LDS reuse between passes (reads already drained)
  }
}

// ---------- in-place causal row softmax: only needed 512-col blocks ----------
__global__ __launch_bounds__(256)
void smax_kernel(unsigned short* __restrict__ S) {
  int id = blockIdx.x;
  int b = id & 7, rb = id >> 3;                 // rb 0..511
  int w = threadIdx.x >> 6, lane = threadIdx.x & 63;
  int row = (511 - rb) * 4 + w;                 // biggest rows dispatched first
  unsigned short* rp = S + ((size_t)b * T_ + row) * T_;
  const int nj = (row >> 9) + 1;                // 1..4 column blocks needed

  bf16x8 d0, d1, d2, d3;
  d0 = *(const bf16x8*)(rp + lane * 8);
  if (nj > 1) d1 = *(const bf16x8*)(rp + 512 + lane * 8);
  if (nj > 2) d2 = *(const bf16x8*)(rp + 1024 + lane * 8);
  if (nj > 3) d3 = *(const bf16x8*)(rp + 1536 + lane * 8);

  float v0[8], v1[8], v2[8], v3[8];
  float mx = -1e30f;
#define PROC(VV, DD, BASE) do { \
    _Pragma("unroll") \
    for (int e = 0; e < 8; ++e) { \
      int col = (BASE) + lane * 8 + e; \
      float f = bf2f((unsigned short)DD[e]); \
      f = (col <= row) ? f : -1e30f; \
      VV[e] = f; mx = fmaxf(mx, f); \
    } } while (0)
  PROC(v0, d0, 0);
  if (nj > 1) PROC(v1, d1, 512);
  if (nj > 2) PROC(v2, d2, 1024);
  if (nj > 3) PROC(v3, d3, 1536);
#undef PROC
#pragma unroll
  for (int msk = 1; msk <= 32; msk <<= 1) mx = fmaxf(mx, __shfl_xor(mx, msk));

  float s = 0.f;
#define EXPS(VV) do { \
    _Pragma("unroll") \
    for (int e = 0; e < 8; ++e) { VV[e] = __expf(VV[e] - mx); s += VV[e]; } } while (0)
  EXPS(v0);
  if (nj > 1) EXPS(v1);
  if (nj > 2) EXPS(v2);
  if (nj > 3) EXPS(v3);
#undef EXPS
#pragma unroll
  for (int msk = 1; msk <= 32; msk <<= 1) s += __shfl_xor(s, msk);
  float inv = 1.0f / s;

#define WRB(VV, BASE) do { \
    bf16x8 o; \
    _Pragma("unroll") \
    for (int e = 0; e < 8; ++e) o[e] = (short)f2bf(VV[e] * inv); \
    *(bf16x8*)(rp + (BASE) + lane * 8) = o; } while (0)
  WRB(v0, 0);
  if (nj > 1) WRB(v1, 512);
  if (nj > 2) WRB(v2, 1024);
  if (nj > 3) WRB(v3, 1536);
#undef WRB
}

// ---------- O = P V, causal (K-range = (mb+1)*128), fp32 out ----------
__global__ __launch_bounds__(256, 2)
void pv_kernel(const unsigned short* __restrict__ P, const unsigned short* __restrict__ vT,
               float* __restrict__ out) {
  __shared__ short L[32768];   // 64KB double-buffered
  int id = blockIdx.x;
  int b = id & 7, u = id >> 3;
  int mb = 15 - (u >> 3);                  // biggest K-range first (load balance)
  int nb = u & 7;                          // d-block 0..7
  const size_t bT = (size_t)b * T_;
  int tid = threadIdx.x, lane = tid & 63, wid = tid >> 6;
  int wm = (wid >> 1) * 64, wn = (wid & 1) * 64;

  f32x4 acc[4][4];
#pragma unroll
  for (int i = 0; i < 4; ++i)
#pragma unroll
    for (int j = 0; j < 4; ++j)
#pragma unroll
      for (int r = 0; r < 4; ++r) acc[i][j][r] = 0.f;

  gemm_core_pipe(P + (bT + mb * 128) * (size_t)T_, T_,
                 vT + (size_t)(nb * 128) * M_ + bT, M_,
                 (mb + 1) * 2, L, lane, wid, acc);

#pragma unroll
  for (int nt = 0; nt < 4; ++nt) {
    int gcol = nb * 128 + wn + nt * 16 + (lane & 15);
#pragma unroll
    for (int mt = 0; mt < 4; ++mt) {
      int grow = mb * 128 + wm + mt * 16 + (lane >> 4) * 4;
#pragma unroll
      for (int r = 0; r < 4; ++r)
        out[(bT + grow + r) * (size_t)H_ + gcol] = acc[mt][nt][r];
    }
  }
}

extern "C" void kernel_launch(void* const* d_in, const int* in_sizes, int n_in,
                              void* d_out, int out_size, void* d_ws, size_t ws_size,
                              hipStream_t stream) {
  const float* x  = (const float*)d_in[0];
  const float* Wq = (const float*)d_in[1];
  const float* bq = (const float*)d_in[2];
  const float* Wk = (const float*)d_in[3];
  const float* bk = (const float*)d_in[4];
  const float* Wv = (const float*)d_in[5];
  const float* bv = (const float*)d_in[6];
  float* out = (float*)d_out;

  unsigned short* ws = (unsigned short*)d_ws;
  unsigned short* xb  = ws;                              // M x E bf16      (32MB)
  unsigned short* wqT = xb  + (size_t)M_ * E_;           // H x E bf16
  unsigned short* wkT = wqT + (size_t)E_ * H_;
  unsigned short* wvT = wkT + (size_t)E_ * H_;
  unsigned short* qb  = wvT + (size_t)E_ * H_;           // M x H bf16      (32MB)
  unsigned short* kbp = qb  + (size_t)M_ * H_;           // M x H bf16
  unsigned short* vTp = kbp + (size_t)M_ * H_;           // H x M bf16 (V transposed)
  unsigned short* Sp  = vTp + (size_t)M_ * H_;           // B x T x T bf16  (67MB) S, then P in-place

  conv_fused_kernel<<<dim3(8192 + 3072), 256, 0, stream>>>(x, xb, Wq, Wk, Wv, wqT, wkT, wvT);
  gemm_qkv_kernel<<<dim3(24, 128), 256, 0, stream>>>(xb, wqT, wkT, wvT, bq, bk, bv, qb, kbp, vTp);
  sgemm_kernel<<<dim3(1024), 256, 0, stream>>>(qb, kbp, Sp);
  smax_kernel<<<dim3(512 * 8), 256, 0, stream>>>(Sp);
  pv_kernel<<<dim3(128 * 8), 256, 0, stream>>>(Sp, vTp, out);
}

// Round 21
// 241.762 us; speedup vs baseline: 1.0062x; 1.0062x over previous
//
#include <hip/hip_runtime.h>
#include <hip/hip_bf16.h>
#include <stdint.h>

#define B_ 8
#define T_ 2048
#define E_ 1024
#define H_ 1024
#define M_ (B_*T_)   // 16384

typedef __attribute__((ext_vector_type(8))) short bf16x8;
typedef __attribute__((ext_vector_type(4))) float f32x4;

__device__ __forceinline__ unsigned short f2bf(float f) {
  union { float f; unsigned int u; } v; v.f = f;
  unsigned int u = v.u;
  unsigned int r = u + 0x7fffu + ((u >> 16) & 1u);   // RNE (inputs finite)
  return (unsigned short)(r >> 16);
}

__device__ __forceinline__ float bf2f(unsigned short s) {
  union { unsigned int u; float f; } v; v.u = ((unsigned int)s) << 16;
  return v.f;
}

// async global->LDS, 16B per lane; LDS dest = wave-uniform base + lane*16
__device__ __forceinline__ void gload_lds16(const void* g, void* l) {
  __builtin_amdgcn_global_load_lds((const __attribute__((address_space(1))) void*)g,
                                   (__attribute__((address_space(3))) void*)l, 16, 0, 0);
}

#define MEMFENCE asm volatile("" ::: "memory")
#define BARRIER() do { MEMFENCE; __builtin_amdgcn_s_barrier(); MEMFENCE; } while (0)

// ---------- fused conversions: x->bf16 (blocks 0..8191) + W transpose (8192..11263) ----------
__global__ void conv_fused_kernel(const float* __restrict__ x, unsigned short* __restrict__ xb,
                                  const float* __restrict__ W0, const float* __restrict__ W1,
                                  const float* __restrict__ W2,
                                  unsigned short* __restrict__ T0, unsigned short* __restrict__ T1,
                                  unsigned short* __restrict__ T2) {
  __shared__ float tile[32][33];
  const int bid = blockIdx.x;
  if (bid < 8192) {
    // conv_x: 8 elems / thread
    int i = bid * 256 + threadIdx.x;
    const float4* src = (const float4*)(x + (size_t)i * 8);
    float4 a = src[0], b = src[1];
    uint4 o;
    o.x = (unsigned)f2bf(a.x) | ((unsigned)f2bf(a.y) << 16);
    o.y = (unsigned)f2bf(a.z) | ((unsigned)f2bf(a.w) << 16);
    o.z = (unsigned)f2bf(b.x) | ((unsigned)f2bf(b.y) << 16);
    o.w = (unsigned)f2bf(b.z) | ((unsigned)f2bf(b.w) << 16);
    *(uint4*)(xb + (size_t)i * 8) = o;
    return;
  }
  // conv_wT: W (E x H) -> wT (H x E) bf16, 32x32 tiles, float4 loads + ushort4 stores
  int id = bid - 8192;                 // 0..3071
  int z = id >> 10;                    // 0..2
  int rem = id & 1023;
  int k0 = (rem & 31) * 32;
  int n0 = (rem >> 5) * 32;
  const float* W = (z == 0) ? W0 : (z == 1) ? W1 : W2;
  unsigned short* Tt = (z == 0) ? T0 : (z == 1) ? T1 : T2;
  int t = threadIdx.x;
  int r = t >> 3, c4 = (t & 7) * 4;
  float4 v = *(const float4*)(W + (size_t)(k0 + r) * H_ + n0 + c4);
  tile[r][c4 + 0] = v.x; tile[r][c4 + 1] = v.y;
  tile[r][c4 + 2] = v.z; tile[r][c4 + 3] = v.w;
  __syncthreads();
  ushort4 o;
  o.x = f2bf(tile[c4 + 0][r]);
  o.y = f2bf(tile[c4 + 1][r]);
  o.z = f2bf(tile[c4 + 2][r]);
  o.w = f2bf(tile[c4 + 3][r]);
  *(ushort4*)(Tt + (size_t)(n0 + r) * E_ + k0 + c4) = o;
}

// ========== pipelined 128x128 core (4 waves, dbuf 64KB, counted vmcnt, 2 blocks/CU) ==========
// LDS buffer layout (bytes): A0 @0, B0 @16384, A1 @32768, B1 @49152.
__device__ __forceinline__ void stage128(const unsigned short* __restrict__ p, size_t stride,
                                         int kb0, short* buf, int lane, int wid) {
  const int srow = wid * 8 + (lane >> 3);
  const int scol = ((lane & 7) ^ (srow & 7)) * 8;
  short* l = buf + wid * 512;
#pragma unroll
  for (int i = 0; i < 4; ++i)
    gload_lds16(p + (size_t)(i * 32 + srow) * stride + kb0 + scol, l + i * 2048);
}

__device__ __forceinline__ void gemm_core_pipe(const unsigned short* __restrict__ Ap, size_t sA,
                                               const unsigned short* __restrict__ Bp, size_t sB,
                                               int NT, short* L, int lane, int wid, f32x4 acc[4][4]) {
  const int lo = lane & 15, hi = lane >> 4;
  const int wm = (wid >> 1) * 64, wn = (wid & 1) * 64;
  const int X0 = (hi << 4) ^ ((lo & 7) << 4);
  const int X1 = ((4 + hi) << 4) ^ ((lo & 7) << 4);
  const int laneA = (wm + lo) << 7;
  const int laneB = (wn + lo) << 7;

  bf16x8 a[4][2], b0[2][2], b1[2][2];

#define STA_(V) do { if ((V) < NT) stage128(Ap, sA, (V) * 64, L + (((V) & 1) ? 16384 : 0), lane, wid); } while (0)
#define STB_(V) do { if ((V) < NT) stage128(Bp, sB, (V) * 64, L + (((V) & 1) ? 24576 : 8192), lane, wid); } while (0)

  STA_(0); STB_(0); STA_(1); STB_(1);
  asm volatile("s_waitcnt vmcnt(8)" ::: "memory");
  BARRIER();
  __builtin_amdgcn_sched_barrier(0);
  {
    const char* Ac = (const char*)L;
    const char* Bc = (const char*)L + 16384;
#pragma unroll
    for (int mt = 0; mt < 4; ++mt) {
      a[mt][0] = *(const bf16x8*)(Ac + laneA + X0 + mt * 2048);
      a[mt][1] = *(const bf16x8*)(Ac + laneA + X1 + mt * 2048);
    }
#pragma unroll
    for (int nt = 0; nt < 2; ++nt) {
      b0[nt][0] = *(const bf16x8*)(Bc + laneB + X0 + nt * 2048);
      b0[nt][1] = *(const bf16x8*)(Bc + laneB + X1 + nt * 2048);
    }
    asm volatile("s_waitcnt lgkmcnt(0)" ::: "memory");
    __builtin_amdgcn_sched_barrier(0);
  }

  for (int U = 0; U < NT; ++U) {
    const char* Bc = (const char*)L + 16384 + (U & 1) * 32768;
    const char* An = (const char*)L + (((U + 1) & 1) ? 32768 : 0);
    const char* Bn = (const char*)L + 16384 + (((U + 1) & 1) ? 32768 : 0);
    const bool pf = (U + 1 < NT);

    // phase 1: MFMA a*b0 || read b1 || stage A(U+2)
    STA_(U + 2);
    __builtin_amdgcn_s_setprio(1);
#pragma unroll
    for (int mt = 0; mt < 2; ++mt)
#pragma unroll
      for (int nt = 0; nt < 2; ++nt)
#pragma unroll
        for (int kt = 0; kt < 2; ++kt)
          acc[mt][nt] = __builtin_amdgcn_mfma_f32_16x16x32_bf16(a[mt][kt], b0[nt][kt], acc[mt][nt], 0, 0, 0);
#pragma unroll
    for (int nt = 0; nt < 2; ++nt) {
      b1[nt][0] = *(const bf16x8*)(Bc + laneB + X0 + 4096 + nt * 2048);
      b1[nt][1] = *(const bf16x8*)(Bc + laneB + X1 + 4096 + nt * 2048);
    }
#pragma unroll
    for (int mt = 2; mt < 4; ++mt)
#pragma unroll
      for (int nt = 0; nt < 2; ++nt)
#pragma unroll
        for (int kt = 0; kt < 2; ++kt)
          acc[mt][nt] = __builtin_amdgcn_mfma_f32_16x16x32_bf16(a[mt][kt], b0[nt][kt], acc[mt][nt], 0, 0, 0);
    __builtin_amdgcn_s_setprio(0);
    asm volatile("s_waitcnt lgkmcnt(0)" ::: "memory");
    if (U + 2 < NT) asm volatile("s_waitcnt vmcnt(4)" ::: "memory");
    else            asm volatile("s_waitcnt vmcnt(0)" ::: "memory");
    BARRIER();
    __builtin_amdgcn_sched_barrier(0);

    // phase 2: MFMA a*b1 || read next a,b0 || stage B(U+2)
    STB_(U + 2);
    __builtin_amdgcn_s_setprio(1);
#pragma unroll
    for (int mt = 0; mt < 2; ++mt)
#pragma unroll
      for (int nt = 0; nt < 2; ++nt)
#pragma unroll
        for (int kt = 0; kt < 2; ++kt)
          acc[mt][2 + nt] = __builtin_amdgcn_mfma_f32_16x16x32_bf16(a[mt][kt], b1[nt][kt], acc[mt][2 + nt], 0, 0, 0);
    if (pf) {
#pragma unroll
      for (int mt = 0; mt < 2; ++mt) {
        a[mt][0] = *(const bf16x8*)(An + laneA + X0 + mt * 2048);
        a[mt][1] = *(const bf16x8*)(An + laneA + X1 + mt * 2048);
      }
#pragma unroll
      for (int nt = 0; nt < 2; ++nt) {
        b0[nt][0] = *(const bf16x8*)(Bn + laneB + X0 + nt * 2048);
        b0[nt][1] = *(const bf16x8*)(Bn + laneB + X1 + nt * 2048);
      }
    }
#pragma unroll
    for (int mt = 2; mt < 4; ++mt)
#pragma unroll
      for (int nt = 0; nt < 2; ++nt)
#pragma unroll
        for (int kt = 0; kt < 2; ++kt)
          acc[mt][2 + nt] = __builtin_amdgcn_mfma_f32_16x16x32_bf16(a[mt][kt], b1[nt][kt], acc[mt][2 + nt], 0, 0, 0);
    if (pf) {
#pragma unroll
      for (int mt = 2; mt < 4; ++mt) {
        a[mt][0] = *(const bf16x8*)(An + laneA + X0 + mt * 2048);
        a[mt][1] = *(const bf16x8*)(An + laneA + X1 + mt * 2048);
      }
    }
    __builtin_amdgcn_s_setprio(0);
    asm volatile("s_waitcnt lgkmcnt(0)" ::: "memory");
    BARRIER();
    __builtin_amdgcn_sched_barrier(0);
  }
#undef STA_
#undef STB_
}

// ---------- fused QKV GEMM on the pipelined 128x128 core ----------
// grid: (24 = which*8 + n-tile, 128 M-tiles). x fastest -> A-panel L2 sharing.
__global__ __launch_bounds__(256, 2)
void gemm_qkv_kernel(const unsigned short* __restrict__ xb,
                     const unsigned short* __restrict__ wqT, const unsigned short* __restrict__ wkT,
                     const unsigned short* __restrict__ wvT,
                     const float* __restrict__ bq, const float* __restrict__ bk,
                     const float* __restrict__ bv,
                     unsigned short* __restrict__ qb, unsigned short* __restrict__ kb,
                     unsigned short* __restrict__ vb) {
  __shared__ short L[32768];   // 64KB double-buffered
  const int which = blockIdx.x >> 3;
  const int ncol0 = (blockIdx.x & 7) * 128;
  const unsigned short* Bt = (which == 0) ? wqT : (which == 1) ? wkT : wvT;
  const float* bias = (which == 0) ? bq : (which == 1) ? bk : bv;
  unsigned short* outp = (which == 0) ? qb : (which == 1) ? kb : vb;
  const int m0 = blockIdx.y * 128;
  int tid = threadIdx.x, lane = tid & 63, wid = tid >> 6;
  int wm = (wid >> 1) * 64, wn = (wid & 1) * 64;

  f32x4 acc[4][4];
#pragma unroll
  for (int i = 0; i < 4; ++i)
#pragma unroll
    for (int j = 0; j < 4; ++j)
#pragma unroll
      for (int r = 0; r < 4; ++r) acc[i][j][r] = 0.f;

  gemm_core_pipe(xb + (size_t)m0 * E_, E_,
                 Bt + (size_t)ncol0 * E_, E_, E_ / 64,
                 L, lane, wid, acc);

  if (which == 2) {
    // transposed write: vT[d = gcol][m = grow..grow+3], 8B packed
#pragma unroll
    for (int nt = 0; nt < 4; ++nt) {
      int gcol = ncol0 + wn + nt * 16 + (lane & 15);
      float bb = bias[gcol];
#pragma unroll
      for (int mt = 0; mt < 4; ++mt) {
        int grow = m0 + wm + mt * 16 + (lane >> 4) * 4;
        ushort4 o2;
        o2.x = f2bf(acc[mt][nt][0] + bb);
        o2.y = f2bf(acc[mt][nt][1] + bb);
        o2.z = f2bf(acc[mt][nt][2] + bb);
        o2.w = f2bf(acc[mt][nt][3] + bb);
        *(ushort4*)(outp + (size_t)gcol * M_ + grow) = o2;
      }
    }
  } else {
#pragma unroll
    for (int nt = 0; nt < 4; ++nt) {
      int gcol = ncol0 + wn + nt * 16 + (lane & 15);
      float bb = bias[gcol];
#pragma unroll
      for (int mt = 0; mt < 4; ++mt) {
        int grow = m0 + wm + mt * 16 + (lane >> 4) * 4;
#pragma unroll
        for (int r = 0; r < 4; ++r)
          outp[(size_t)(grow + r) * H_ + gcol] = f2bf(acc[mt][nt][r] + bb);
      }
    }
  }
}

// ---------- S = (Q K^T) * scale, causal lower-tri 128x128 tiles, bf16 out ----------
// 1024 blocks (exactly 2 dispatch waves @2/CU); blocks 0..63 do a second tile.
__global__ __launch_bounds__(256, 2)
void sgemm_kernel(const unsigned short* __restrict__ qb, const unsigned short* __restrict__ kb,
                  unsigned short* __restrict__ S) {
  __shared__ short L[32768];   // 64KB double-buffered
  int tid = threadIdx.x, lane = tid & 63, wid = tid >> 6;
  int wm = (wid >> 1) * 64, wn = (wid & 1) * 64;
  const int npass = (blockIdx.x < 64) ? 2 : 1;

  for (int pass = 0; pass < npass; ++pass) {
    int id = blockIdx.x + pass * 1024;
    int b = id & 7, t = id >> 3;            // batch-fastest: same batch -> same XCD
    int mb = 0;
    while ((mb + 1) * (mb + 2) / 2 <= t) ++mb;
    int nb = t - mb * (mb + 1) / 2;         // nb <= mb (lower triangle)
    const size_t bT = (size_t)b * T_;

    f32x4 acc[4][4];
#pragma unroll
    for (int i = 0; i < 4; ++i)
#pragma unroll
      for (int j = 0; j < 4; ++j)
#pragma unroll
        for (int r = 0; r < 4; ++r) acc[i][j][r] = 0.f;

    gemm_core_pipe(qb + (bT + mb * 128) * (size_t)H_, H_,
                   kb + (bT + nb * 128) * (size_t)H_, H_, H_ / 64,
                   L, lane, wid, acc);

#pragma unroll
    for (int nt = 0; nt < 4; ++nt) {
      int gcol = nb * 128 + wn + nt * 16 + (lane & 15);
#pragma unroll
      for (int mt = 0; mt < 4; ++mt) {
        int grow = mb * 128 + wm + mt * 16 + (lane >> 4) * 4;
#pragma unroll
        for (int r = 0; r < 4; ++r)
          S[(bT + grow + r) * (size_t)T_ + gcol] = f2bf(acc[mt][nt][r] * 0.03125f);
      }
    }
    if (pass + 1 < npass) { BARRIER(); }   // LDS reuse between passes (reads already drained)
  }
}

// ---------- in-place causal row softmax: only needed 512-col blocks ----------
__global__ __launch_bounds__(256)
void smax_kernel(unsigned short* __restrict__ S) {
  int id = blockIdx.x;
  int b = id & 7, rb = id >> 3;                 // rb 0..511
  int w = threadIdx.x >> 6, lane = threadIdx.x & 63;
  int row = (511 - rb) * 4 + w;                 // biggest rows dispatched first
  unsigned short* rp = S + ((size_t)b * T_ + row) * T_;
  const int nj = (row >> 9) + 1;                // 1..4 column blocks needed

  bf16x8 d0, d1, d2, d3;
  d0 = *(const bf16x8*)(rp + lane * 8);
  if (nj > 1) d1 = *(const bf16x8*)(rp + 512 + lane * 8);
  if (nj > 2) d2 = *(const bf16x8*)(rp + 1024 + lane * 8);
  if (nj > 3) d3 = *(const bf16x8*)(rp + 1536 + lane * 8);

  float v0[8], v1[8], v2[8], v3[8];
  float mx = -1e30f;
#define PROC(VV, DD, BASE) do { \
    _Pragma("unroll") \
    for (int e = 0; e < 8; ++e) { \
      int col = (BASE) + lane * 8 + e; \
      float f = bf2f((unsigned short)DD[e]); \
      f = (col <= row) ? f : -1e30f; \
      VV[e] = f; mx = fmaxf(mx, f); \
    } } while (0)
  PROC(v0, d0, 0);
  if (nj > 1) PROC(v1, d1, 512);
  if (nj > 2) PROC(v2, d2, 1024);
  if (nj > 3) PROC(v3, d3, 1536);
#undef PROC
#pragma unroll
  for (int msk = 1; msk <= 32; msk <<= 1) mx = fmaxf(mx, __shfl_xor(mx, msk));

  float s = 0.f;
#define EXPS(VV) do { \
    _Pragma("unroll") \
    for (int e = 0; e < 8; ++e) { VV[e] = __expf(VV[e] - mx); s += VV[e]; } } while (0)
  EXPS(v0);
  if (nj > 1) EXPS(v1);
  if (nj > 2) EXPS(v2);
  if (nj > 3) EXPS(v3);
#undef EXPS
#pragma unroll
  for (int msk = 1; msk <= 32; msk <<= 1) s += __shfl_xor(s, msk);
  float inv = 1.0f / s;

#define WRB(VV, BASE) do { \
    bf16x8 o; \
    _Pragma("unroll") \
    for (int e = 0; e < 8; ++e) o[e] = (short)f2bf(VV[e] * inv); \
    *(bf16x8*)(rp + (BASE) + lane * 8) = o; } while (0)
  WRB(v0, 0);
  if (nj > 1) WRB(v1, 512);
  if (nj > 2) WRB(v2, 1024);
  if (nj > 3) WRB(v3, 1536);
#undef WRB
}

// ---------- O = P V, causal (K-range = (mb+1)*128), fp32 out ----------
__global__ __launch_bounds__(256, 2)
void pv_kernel(const unsigned short* __restrict__ P, const unsigned short* __restrict__ vT,
               float* __restrict__ out) {
  __shared__ short L[32768];   // 64KB double-buffered
  int id = blockIdx.x;
  int b = id & 7, u = id >> 3;
  int mb = 15 - (u >> 3);                  // biggest K-range first (load balance)
  int nb = u & 7;                          // d-block 0..7
  const size_t bT = (size_t)b * T_;
  int tid = threadIdx.x, lane = tid & 63, wid = tid >> 6;
  int wm = (wid >> 1) * 64, wn = (wid & 1) * 64;

  f32x4 acc[4][4];
#pragma unroll
  for (int i = 0; i < 4; ++i)
#pragma unroll
    for (int j = 0; j < 4; ++j)
#pragma unroll
      for (int r = 0; r < 4; ++r) acc[i][j][r] = 0.f;

  gemm_core_pipe(P + (bT + mb * 128) * (size_t)T_, T_,
                 vT + (size_t)(nb * 128) * M_ + bT, M_,
                 (mb + 1) * 2, L, lane, wid, acc);

#pragma unroll
  for (int nt = 0; nt < 4; ++nt) {
    int gcol = nb * 128 + wn + nt * 16 + (lane & 15);
#pragma unroll
    for (int mt = 0; mt < 4; ++mt) {
      int grow = mb * 128 + wm + mt * 16 + (lane >> 4) * 4;
#pragma unroll
      for (int r = 0; r < 4; ++r)
        out[(bT + grow + r) * (size_t)H_ + gcol] = acc[mt][nt][r];
    }
  }
}

extern "C" void kernel_launch(void* const* d_in, const int* in_sizes, int n_in,
                              void* d_out, int out_size, void* d_ws, size_t ws_size,
                              hipStream_t stream) {
  const float* x  = (const float*)d_in[0];
  const float* Wq = (const float*)d_in[1];
  const float* bq = (const float*)d_in[2];
  const float* Wk = (const float*)d_in[3];
  const float* bk = (const float*)d_in[4];
  const float* Wv = (const float*)d_in[5];
  const float* bv = (const float*)d_in[6];
  float* out = (float*)d_out;

  unsigned short* ws = (unsigned short*)d_ws;
  unsigned short* xb  = ws;                              // M x E bf16      (32MB)
  unsigned short* wqT = xb  + (size_t)M_ * E_;           // H x E bf16
  unsigned short* wkT = wqT + (size_t)E_ * H_;
  unsigned short* wvT = wkT + (size_t)E_ * H_;
  unsigned short* qb  = wvT + (size_t)E_ * H_;           // M x H bf16      (32MB)
  unsigned short* kbp = qb  + (size_t)M_ * H_;           // M x H bf16
  unsigned short* vTp = kbp + (size_t)M_ * H_;           // H x M bf16 (V transposed)
  unsigned short* Sp  = vTp + (size_t)M_ * H_;           // B x T x T bf16  (67MB) S, then P in-place

  conv_fused_kernel<<<dim3(8192 + 3072), 256, 0, stream>>>(x, xb, Wq, Wk, Wv, wqT, wkT, wvT);
  gemm_qkv_kernel<<<dim3(24, 128), 256, 0, stream>>>(xb, wqT, wkT, wvT, bq, bk, bv, qb, kbp, vTp);
  sgemm_kernel<<<dim3(1024), 256, 0, stream>>>(qb, kbp, Sp);
  smax_kernel<<<dim3(512 * 8), 256, 0, stream>>>(Sp);
  pv_kernel<<<dim3(128 * 8), 256, 0, stream>>>(Sp, vTp, out);
}